// Round 9
// baseline (122.243 us; speedup 1.0000x reference)
//
#include <hip/hip_runtime.h>
#include <math.h>

#define IN_DIM 16
#define HID 128
#define NEG 0.2f

__device__ __forceinline__ float lrelu(float a) { return a > 0.f ? a : NEG * a; }

// offsets[i] computed on the fly from exoff + blockBase (scan3 deleted)
__device__ __forceinline__ int off_at(const int* __restrict__ exoff,
                                      const int* __restrict__ blockBase,
                                      int i, int n_nodes, int ecnt) {
    return (i >= n_nodes) ? ecnt : (exoff[i] + blockBase[i >> 9]);
}

// ---------------- precompute (wave-parallel) + zero counts/ticket --
// A (32-dim per node) = per-relation softmax-weighted input sums.
// layer-2 per-node needs [xr2_r0(3) xr2_r1(3) sq2(2) sk2(2)] = A·M + C
// M[dp][o] = sum_c W1[dp][c]·T[c][o],  C[o] = sum_c b1[c]·T[c][o]
// One WAVE per output scalar: waves 0..319 -> M, 320..329 -> C,
// 330..361 -> wq1/wk1 rows. Lanes split the 128-length reduction.
__global__ void __launch_bounds__(256) k_pre(
    const float* __restrict__ W1, const float* __restrict__ q1, const float* __restrict__ k1,
    const float* __restrict__ b1, const float* __restrict__ W2, const float* __restrict__ q2,
    const float* __restrict__ k2,
    float* __restrict__ wq1, float* __restrict__ wk1,
    float* __restrict__ M, float* __restrict__ C,
    int* __restrict__ counts, int* __restrict__ ticket, int n_nodes) {
    int zi = blockIdx.x * 256 + threadIdx.x;
    if (zi < n_nodes) counts[zi] = 0;
    if (zi == 0) *ticket = 0;

    int w = blockIdx.x * 4 + (threadIdx.x >> 6);
    if (w >= 362) return;
    int lane = threadIdx.x & 63;

    auto T = [&](int c, int o) -> float {      // o is wave-uniform
        if (o < 3) return W2[c * 3 + o];
        if (o < 6) return W2[384 + c * 3 + (o - 3)];
        const float* base = (o == 6 || o == 8) ? (W2 + c * 3) : (W2 + 384 + c * 3);
        const float* v = (o < 8) ? q2 : k2;
        return base[0] * v[0] + base[1] * v[1] + base[2] * v[2];
    };

    if (w < 330) {
        bool isC = (w >= 320);
        int o  = isC ? (w - 320) : (w % 10);
        int dp = isC ? 0 : (w / 10);
        float acc = 0.f;
        for (int c = lane; c < HID; c += 64) {
            float left = isC ? b1[c] : W1[dp * HID + c];
            acc += left * T(c, o);
        }
#pragma unroll
        for (int off = 32; off; off >>= 1) acc += __shfl_xor(acc, off);
        if (lane == 0) { if (isC) C[o] = acc; else M[dp * 10 + o] = acc; }
    } else {
        int i = w - 330;                       // 0..31 = r*16+d
        float aq = 0.f, ak = 0.f;
        for (int c = lane; c < HID; c += 64) {
            float wv = W1[i * HID + c];
            aq += wv * q1[c]; ak += wv * k1[c];
        }
#pragma unroll
        for (int off = 32; off; off >>= 1) { aq += __shfl_xor(aq, off); ak += __shfl_xor(ak, off); }
        if (lane == 0) { wq1[i] = aq; wk1[i] = ak; }
    }
}

// ---------------- fused: layer1 score scalars + dst histogram(+rank)
__global__ void __launch_bounds__(256) k_prep(
    const float* __restrict__ x,
    const float* __restrict__ wq1, const float* __restrict__ wk1,
    float* __restrict__ sq1, float* __restrict__ sk1,
    const int* __restrict__ dstp, int* __restrict__ counts, int* __restrict__ rank,
    int n_nodes, int ecnt) {
    __shared__ float wq[2 * IN_DIM], wk[2 * IN_DIM];
    if (threadIdx.x < 2 * IN_DIM) { wq[threadIdx.x] = wq1[threadIdx.x]; wk[threadIdx.x] = wk1[threadIdx.x]; }
    __syncthreads();
    int gid = blockIdx.x * 256 + threadIdx.x;
    if (gid < ecnt) rank[gid] = atomicAdd(&counts[dstp[gid]], 1);
    if (gid < n_nodes) {
        float q0 = 0.f, q1v = 0.f, k0 = 0.f, k1v = 0.f;
        const float4* xp = reinterpret_cast<const float4*>(x + (size_t)gid * IN_DIM);
#pragma unroll
        for (int d4 = 0; d4 < IN_DIM / 4; ++d4) {
            float4 v = xp[d4];
            float vv[4] = {v.x, v.y, v.z, v.w};
#pragma unroll
            for (int j = 0; j < 4; ++j) {
                int d = d4 * 4 + j;
                q0 += vv[j] * wq[d]; q1v += vv[j] * wq[IN_DIM + d];
                k0 += vv[j] * wk[d]; k1v += vv[j] * wk[IN_DIM + d];
            }
        }
        sq1[gid] = q0; sq1[n_nodes + gid] = q1v;
        sk1[gid] = k0; sk1[n_nodes + gid] = k1v;
    }
}

// ---------------- scan: per-block Hillis-Steele + last-block top ---
__global__ void __launch_bounds__(512) k_scan1(
    const int* __restrict__ counts, int* __restrict__ exoff,
    int* __restrict__ blockSums, int* __restrict__ blockBase,
    int* __restrict__ ticket, int n, int nblk) {
    __shared__ int s[512];
    __shared__ int isLast;
    int tid = threadIdx.x;
    int gid = blockIdx.x * 512 + tid;
    int v = (gid < n) ? counts[gid] : 0;
    s[tid] = v;
    __syncthreads();
    for (int off = 1; off < 512; off <<= 1) {
        int t = (tid >= off) ? s[tid - off] : 0;
        __syncthreads();
        s[tid] += t;
        __syncthreads();
    }
    if (gid < n) exoff[gid] = s[tid] - v;
    if (tid == 511) blockSums[blockIdx.x] = s[511];
    __threadfence();
    if (tid == 0) isLast = (atomicAdd(ticket, 1) == (int)gridDim.x - 1);
    __syncthreads();
    if (!isLast) return;
    __threadfence();
    int bv = (tid < nblk) ? blockSums[tid] : 0;
    s[tid] = bv;
    __syncthreads();
    for (int off = 1; off < 128; off <<= 1) {     // nblk < 128
        int u = (tid >= off) ? s[tid - off] : 0;
        __syncthreads();
        s[tid] += u;
        __syncthreads();
    }
    if (tid < nblk) blockBase[tid] = s[tid] - bv;
}

// ---------------- scatter edges into CSR order --------------------
__global__ void __launch_bounds__(256) k_scatter(
    const int* __restrict__ srcp, const int* __restrict__ dstp,
    const int* __restrict__ etp,
    const int* __restrict__ exoff, const int* __restrict__ blockBase,
    const int* __restrict__ rank, int* __restrict__ sorted, int ecnt) {
    int e = blockIdx.x * 256 + threadIdx.x;
    if (e >= ecnt) return;
    int d = dstp[e];
    int o = exoff[d] + blockBase[d >> 9];
    sorted[o + rank[e]] = (etp[e] << 16) | srcp[e];
}

// ---------------- layer1 fused: aggregate -> 10 outputs -----------
// wave per node; single edge pass (no max subtraction: |alpha| << 88).
// Outputs: xr2p[(r*n+node)] = {p0,p1,p2, sk2}, sq2 interleaved [2n,2n+1].
__global__ void __launch_bounds__(256) k_layer1(
    const int* __restrict__ exoff, const int* __restrict__ blockBase,
    const int* __restrict__ sorted,
    const float* __restrict__ sq1, const float* __restrict__ sk1,
    const float* __restrict__ x, const float* __restrict__ M, const float* __restrict__ C,
    float* __restrict__ xr2p, float* __restrict__ sq2,
    int n_nodes, int ecnt) {
    __shared__ float Ml[320], Cl[10];
    __shared__ float Al[4][32];
    for (int i = threadIdx.x; i < 320; i += 256) Ml[i] = M[i];
    if (threadIdx.x < 10)  Cl[threadIdx.x] = C[threadIdx.x];
    __syncthreads();
    int wid = threadIdx.x >> 6, lane = threadIdx.x & 63;
    int n = blockIdx.x * 4 + wid;
    if (n >= n_nodes) return;
    int beg = off_at(exoff, blockBase, n, n_nodes, ecnt);
    int end = off_at(exoff, blockBase, n + 1, n_nodes, ecnt);
    float s0 = sq1[n], s1 = sq1[n_nodes + n];
    // aggregation: d = lane&15 (channel), j = lane>>4 (edge slot, 4-way)
    int d = lane & 15, j = lane >> 4;
    float a0 = 0.f, a1 = 0.f, ds = 0.f;
    for (int e = beg + j; e < end; e += 4) {
        int pk = sorted[e];
        int et = pk >> 16, s = pk & 0xFFFF;
        float w = __expf(lrelu((et ? s1 : s0) + sk1[et * n_nodes + s]));
        ds += w;
        float xv = x[s * IN_DIM + d];
        if (et == 0) a0 += w * xv; else a1 += w * xv;
    }
#pragma unroll
    for (int off = 16; off <= 32; off <<= 1) {
        a0 += __shfl_xor(a0, off);
        a1 += __shfl_xor(a1, off);
        ds += __shfl_xor(ds, off);
    }
    float inv = 1.f / (ds + 1e-16f);
    if (lane < 16) { Al[wid][lane] = a0 * inv; Al[wid][16 + lane] = a1 * inv; }
    // (same-wave LDS write->read; compiler inserts lgkmcnt wait)
    if (lane < 10) {
        float acc = Cl[lane];
#pragma unroll
        for (int dp = 0; dp < 32; ++dp) acc += Al[wid][dp] * Ml[dp * 10 + lane];
        int o = lane;
        if (o < 3)       xr2p[(size_t)n * 4 + o] = acc;
        else if (o < 6)  xr2p[((size_t)n_nodes + n) * 4 + (o - 3)] = acc;
        else if (o == 6) sq2[2 * n] = acc;
        else if (o == 7) sq2[2 * n + 1] = acc;
        else if (o == 8) xr2p[(size_t)n * 4 + 3] = acc;               // sk2 r0
        else             xr2p[((size_t)n_nodes + n) * 4 + 3] = acc;   // sk2 r1
    }
}

// ---------------- layer2 aggregation (16 lanes/node, single pass) -
// per-edge data fully packed in one float4: {p0,p1,p2, sk2}
__global__ void __launch_bounds__(256) k_node2(
    const int* __restrict__ exoff, const int* __restrict__ blockBase,
    const int* __restrict__ sorted,
    const float* __restrict__ sq2, const float* __restrict__ xr2p,
    const float* __restrict__ b2, float* __restrict__ out,
    int n_nodes, int ecnt) {
    int gid = blockIdx.x * 256 + threadIdx.x;
    int n = gid >> 4;
    int l = threadIdx.x & 15;
    if (n >= n_nodes) return;
    int beg = off_at(exoff, blockBase, n, n_nodes, ecnt);
    int end = off_at(exoff, blockBase, n + 1, n_nodes, ecnt);
    if (beg == end) {
        if (l < 3) out[(size_t)n * 3 + l] = b2[l];
        return;
    }
    const float2 sq = *reinterpret_cast<const float2*>(sq2 + 2 * n);
    float lsum = 0.f, a0 = 0.f, a1 = 0.f, a2 = 0.f;
    for (int e = beg + l; e < end; e += 16) {
        int pk = sorted[e];
        int et = pk >> 16, s = pk & 0xFFFF;
        const float4 xr = *reinterpret_cast<const float4*>(xr2p + ((size_t)et * n_nodes + s) * 4);
        float w = __expf(lrelu((et ? sq.y : sq.x) + xr.w));
        lsum += w;
        a0 += w * xr.x; a1 += w * xr.y; a2 += w * xr.z;
    }
#pragma unroll
    for (int off = 8; off; off >>= 1) {
        lsum += __shfl_xor(lsum, off);
        a0 += __shfl_xor(a0, off);
        a1 += __shfl_xor(a1, off);
        a2 += __shfl_xor(a2, off);
    }
    if (l == 0) {
        float inv = 1.f / (lsum + 1e-16f);
        out[(size_t)n * 3 + 0] = a0 * inv + b2[0];
        out[(size_t)n * 3 + 1] = a1 * inv + b2[1];
        out[(size_t)n * 3 + 2] = a2 * inv + b2[2];
    }
}

extern "C" void kernel_launch(void* const* d_in, const int* in_sizes, int n_in,
                              void* d_out, int out_size, void* d_ws, size_t ws_size,
                              hipStream_t stream) {
    const float* x  = (const float*)d_in[0];
    const int*   ei = (const int*)d_in[1];
    const int*   etp = (const int*)d_in[2];
    const float* W1 = (const float*)d_in[3];
    const float* q1 = (const float*)d_in[4];
    const float* k1 = (const float*)d_in[5];
    const float* b1 = (const float*)d_in[6];
    const float* W2 = (const float*)d_in[7];
    const float* q2 = (const float*)d_in[8];
    const float* k2 = (const float*)d_in[9];
    const float* b2 = (const float*)d_in[10];
    float* out = (float*)d_out;

    const int n_nodes = in_sizes[0] / IN_DIM;  // 50000
    const int ecnt    = in_sizes[2];           // 800000
    const int* srcp = ei;
    const int* dstp = ei + ecnt;

    char* wp = (char*)d_ws;
    auto alloc = [&](size_t bytes) -> char* {
        char* p = wp;
        wp += (bytes + 255) & ~(size_t)255;
        return p;
    };
    float* xr2p  = (float*)alloc((size_t)2 * n_nodes * 4 * 4);
    float* sq1   = (float*)alloc((size_t)2 * n_nodes * 4);
    float* sk1   = (float*)alloc((size_t)2 * n_nodes * 4);
    float* sq2   = (float*)alloc((size_t)2 * n_nodes * 4);
    float* wq1   = (float*)alloc(32 * 4);
    float* wk1   = (float*)alloc(32 * 4);
    float* Mbuf  = (float*)alloc(320 * 4);
    float* Cbuf  = (float*)alloc(10 * 4);
    int* counts  = (int*)alloc((size_t)n_nodes * 4);
    int* exoff   = (int*)alloc((size_t)n_nodes * 4);
    int* blockSums = (int*)alloc(512);
    int* blockBase = (int*)alloc(512);
    int* ticket  = (int*)alloc(256);
    int* rank    = (int*)alloc((size_t)ecnt * 4);
    int* sorted  = (int*)alloc((size_t)ecnt * 4);

    int nblk = (n_nodes + 255) / 256;   // 196: covers counts zeroing + precompute waves
    int eblk = (ecnt + 255) / 256;
    int nblk_scan = (n_nodes + 511) / 512;  // 98 < 128

    k_pre<<<nblk, 256, 0, stream>>>(W1, q1, k1, b1, W2, q2, k2, wq1, wk1, Mbuf, Cbuf,
                                    counts, ticket, n_nodes);
    k_prep<<<eblk, 256, 0, stream>>>(x, wq1, wk1, sq1, sk1, dstp, counts, rank, n_nodes, ecnt);
    k_scan1<<<nblk_scan, 512, 0, stream>>>(counts, exoff, blockSums, blockBase, ticket,
                                           n_nodes, nblk_scan);
    k_scatter<<<eblk, 256, 0, stream>>>(srcp, dstp, etp, exoff, blockBase, rank, sorted, ecnt);

    k_layer1<<<(n_nodes + 3) / 4, 256, 0, stream>>>(exoff, blockBase, sorted, sq1, sk1, x,
                                                    Mbuf, Cbuf, xr2p, sq2, n_nodes, ecnt);
    k_node2<<<(n_nodes * 16 + 255) / 256, 256, 0, stream>>>(exoff, blockBase, sorted, sq2,
                                                            xr2p, b2, out, n_nodes, ecnt);
}

// Round 10
// 108.652 us; speedup vs baseline: 1.1251x; 1.1251x over previous
//
#include <hip/hip_runtime.h>
#include <math.h>

#define IN_DIM 16
#define HID 128
#define NEG 0.2f

__device__ __forceinline__ float lrelu(float a) { return a > 0.f ? a : NEG * a; }

// ---------------- precompute (wave-parallel) + zero counts ---------
// A (32-dim per node) = per-relation softmax-weighted input sums.
// layer-2 per-node needs [xr2_r0(3) xr2_r1(3) sq2(2) sk2(2)] = A·M + C
// M[dp][o] = sum_c W1[dp][c]·T[c][o],  C[o] = sum_c b1[c]·T[c][o]
// One WAVE per output scalar: waves 0..319 -> M, 320..329 -> C,
// 330..361 -> wq1/wk1 rows. Lanes split the 128-length reduction.
__global__ void __launch_bounds__(256) k_pre(
    const float* __restrict__ W1, const float* __restrict__ q1, const float* __restrict__ k1,
    const float* __restrict__ b1, const float* __restrict__ W2, const float* __restrict__ q2,
    const float* __restrict__ k2,
    float* __restrict__ wq1, float* __restrict__ wk1,
    float* __restrict__ M, float* __restrict__ C,
    int* __restrict__ counts, int n_nodes) {
    int zi = blockIdx.x * 256 + threadIdx.x;
    if (zi < n_nodes) counts[zi] = 0;          // replaces 40us hipMemsetAsync

    int w = blockIdx.x * 4 + (threadIdx.x >> 6);
    if (w >= 362) return;
    int lane = threadIdx.x & 63;

    auto T = [&](int c, int o) -> float {      // o is wave-uniform
        if (o < 3) return W2[c * 3 + o];
        if (o < 6) return W2[384 + c * 3 + (o - 3)];
        const float* base = (o == 6 || o == 8) ? (W2 + c * 3) : (W2 + 384 + c * 3);
        const float* v = (o < 8) ? q2 : k2;
        return base[0] * v[0] + base[1] * v[1] + base[2] * v[2];
    };

    if (w < 330) {
        bool isC = (w >= 320);
        int o  = isC ? (w - 320) : (w % 10);
        int dp = isC ? 0 : (w / 10);
        float acc = 0.f;
        for (int c = lane; c < HID; c += 64) {
            float left = isC ? b1[c] : W1[dp * HID + c];
            acc += left * T(c, o);
        }
#pragma unroll
        for (int off = 32; off; off >>= 1) acc += __shfl_xor(acc, off);
        if (lane == 0) { if (isC) C[o] = acc; else M[dp * 10 + o] = acc; }
    } else {
        int i = w - 330;                       // 0..31 = r*16+d
        float aq = 0.f, ak = 0.f;
        for (int c = lane; c < HID; c += 64) {
            float wv = W1[i * HID + c];
            aq += wv * q1[c]; ak += wv * k1[c];
        }
#pragma unroll
        for (int off = 32; off; off >>= 1) { aq += __shfl_xor(aq, off); ak += __shfl_xor(ak, off); }
        if (lane == 0) { wq1[i] = aq; wk1[i] = ak; }
    }
}

// ---------------- fused: layer1 score scalars + dst histogram(+rank)
__global__ void __launch_bounds__(256) k_prep(
    const float* __restrict__ x,
    const float* __restrict__ wq1, const float* __restrict__ wk1,
    float* __restrict__ sq1, float* __restrict__ sk1,
    const int* __restrict__ dstp, int* __restrict__ counts, int* __restrict__ rank,
    int n_nodes, int ecnt) {
    __shared__ float wq[2 * IN_DIM], wk[2 * IN_DIM];
    if (threadIdx.x < 2 * IN_DIM) { wq[threadIdx.x] = wq1[threadIdx.x]; wk[threadIdx.x] = wk1[threadIdx.x]; }
    __syncthreads();
    int gid = blockIdx.x * 256 + threadIdx.x;
    if (gid < ecnt) rank[gid] = atomicAdd(&counts[dstp[gid]], 1);
    if (gid < n_nodes) {
        float q0 = 0.f, q1v = 0.f, k0 = 0.f, k1v = 0.f;
        const float4* xp = reinterpret_cast<const float4*>(x + (size_t)gid * IN_DIM);
#pragma unroll
        for (int d4 = 0; d4 < IN_DIM / 4; ++d4) {
            float4 v = xp[d4];
            float vv[4] = {v.x, v.y, v.z, v.w};
#pragma unroll
            for (int j = 0; j < 4; ++j) {
                int d = d4 * 4 + j;
                q0 += vv[j] * wq[d]; q1v += vv[j] * wq[IN_DIM + d];
                k0 += vv[j] * wk[d]; k1v += vv[j] * wk[IN_DIM + d];
            }
        }
        sq1[gid] = q0; sq1[n_nodes + gid] = q1v;
        sk1[gid] = k0; sk1[n_nodes + gid] = k1v;
    }
}

// ---------------- 3-kernel grid-parallel scan (round-8 proven) ----
__global__ void k_scan1(const int* __restrict__ counts, int* __restrict__ exoff,
                        int* __restrict__ blockSums, int n) {
    __shared__ int s[512];
    int tid = threadIdx.x;
    int gid = blockIdx.x * 512 + tid;
    int v = (gid < n) ? counts[gid] : 0;
    s[tid] = v;
    __syncthreads();
    for (int off = 1; off < 512; off <<= 1) {
        int t = (tid >= off) ? s[tid - off] : 0;
        __syncthreads();
        s[tid] += t;
        __syncthreads();
    }
    if (gid < n) exoff[gid] = s[tid] - v;
    if (tid == 511) blockSums[blockIdx.x] = s[511];
}

__global__ void k_scan2(const int* __restrict__ blockSums, int* __restrict__ blockBase, int nblk) {
    __shared__ int s[128];
    int t = threadIdx.x;
    int v = (t < nblk) ? blockSums[t] : 0;
    s[t] = v;
    __syncthreads();
    for (int off = 1; off < 128; off <<= 1) {
        int u = (t >= off) ? s[t - off] : 0;
        __syncthreads();
        s[t] += u;
        __syncthreads();
    }
    if (t < nblk) blockBase[t] = s[t] - v;
}

__global__ void k_scan3(const int* __restrict__ exoff, const int* __restrict__ blockBase,
                        int* __restrict__ offsets, int n_nodes, int ecnt) {
    int i = blockIdx.x * 256 + threadIdx.x;
    if (i < n_nodes) offsets[i] = exoff[i] + blockBase[i >> 9];
    if (i == 0) offsets[n_nodes] = ecnt;
}

// ---------------- scatter edges into CSR order --------------------
__global__ void __launch_bounds__(256) k_scatter(
    const int* __restrict__ srcp, const int* __restrict__ dstp,
    const int* __restrict__ etp, const int* __restrict__ offsets,
    const int* __restrict__ rank, int* __restrict__ sorted, int ecnt) {
    int e = blockIdx.x * 256 + threadIdx.x;
    if (e >= ecnt) return;
    int d = dstp[e];
    sorted[offsets[d] + rank[e]] = (etp[e] << 16) | srcp[e];
}

// ---------------- layer1 fused: aggregate -> 10 outputs -----------
// wave per node; single edge pass (no max subtraction: |alpha| << 88).
// Outputs: xr2p[(r*n+node)] = {p0,p1,p2, sk2}, sq2 interleaved [2n,2n+1].
__global__ void __launch_bounds__(256) k_layer1(
    const int* __restrict__ offsets, const int* __restrict__ sorted,
    const float* __restrict__ sq1, const float* __restrict__ sk1,
    const float* __restrict__ x, const float* __restrict__ M, const float* __restrict__ C,
    float* __restrict__ xr2p, float* __restrict__ sq2,
    int n_nodes) {
    __shared__ float Ml[320], Cl[10];
    __shared__ float Al[4][32];
    for (int i = threadIdx.x; i < 320; i += 256) Ml[i] = M[i];
    if (threadIdx.x < 10)  Cl[threadIdx.x] = C[threadIdx.x];
    __syncthreads();
    int wid = threadIdx.x >> 6, lane = threadIdx.x & 63;
    int n = blockIdx.x * 4 + wid;
    if (n >= n_nodes) return;
    int beg = offsets[n], end = offsets[n + 1];
    float s0 = sq1[n], s1 = sq1[n_nodes + n];
    // aggregation: d = lane&15 (channel), j = lane>>4 (edge slot, 4-way)
    int d = lane & 15, j = lane >> 4;
    float a0 = 0.f, a1 = 0.f, ds = 0.f;
    for (int e = beg + j; e < end; e += 4) {
        int pk = sorted[e];
        int et = pk >> 16, s = pk & 0xFFFF;
        float w = __expf(lrelu((et ? s1 : s0) + sk1[et * n_nodes + s]));
        ds += w;
        float xv = x[s * IN_DIM + d];
        if (et == 0) a0 += w * xv; else a1 += w * xv;
    }
#pragma unroll
    for (int off = 16; off <= 32; off <<= 1) {
        a0 += __shfl_xor(a0, off);
        a1 += __shfl_xor(a1, off);
        ds += __shfl_xor(ds, off);
    }
    float inv = 1.f / (ds + 1e-16f);
    if (lane < 16) { Al[wid][lane] = a0 * inv; Al[wid][16 + lane] = a1 * inv; }
    // (same-wave LDS write->read; compiler inserts lgkmcnt wait)
    if (lane < 10) {
        float acc = Cl[lane];
#pragma unroll
        for (int dp = 0; dp < 32; ++dp) acc += Al[wid][dp] * Ml[dp * 10 + lane];
        int o = lane;
        if (o < 3)       xr2p[(size_t)n * 4 + o] = acc;
        else if (o < 6)  xr2p[((size_t)n_nodes + n) * 4 + (o - 3)] = acc;
        else if (o == 6) sq2[2 * n] = acc;
        else if (o == 7) sq2[2 * n + 1] = acc;
        else if (o == 8) xr2p[(size_t)n * 4 + 3] = acc;               // sk2 r0
        else             xr2p[((size_t)n_nodes + n) * 4 + 3] = acc;   // sk2 r1
    }
}

// ---------------- layer2 aggregation (16 lanes/node, single pass) -
// per-edge data fully packed in one float4: {p0,p1,p2, sk2}
__global__ void __launch_bounds__(256) k_node2(
    const int* __restrict__ offsets, const int* __restrict__ sorted,
    const float* __restrict__ sq2, const float* __restrict__ xr2p,
    const float* __restrict__ b2, float* __restrict__ out,
    int n_nodes) {
    int gid = blockIdx.x * 256 + threadIdx.x;
    int n = gid >> 4;
    int l = threadIdx.x & 15;
    if (n >= n_nodes) return;
    int beg = offsets[n], end = offsets[n + 1];
    if (beg == end) {
        if (l < 3) out[(size_t)n * 3 + l] = b2[l];
        return;
    }
    const float2 sq = *reinterpret_cast<const float2*>(sq2 + 2 * n);
    float lsum = 0.f, a0 = 0.f, a1 = 0.f, a2 = 0.f;
    for (int e = beg + l; e < end; e += 16) {
        int pk = sorted[e];
        int et = pk >> 16, s = pk & 0xFFFF;
        const float4 xr = *reinterpret_cast<const float4*>(xr2p + ((size_t)et * n_nodes + s) * 4);
        float w = __expf(lrelu((et ? sq.y : sq.x) + xr.w));
        lsum += w;
        a0 += w * xr.x; a1 += w * xr.y; a2 += w * xr.z;
    }
#pragma unroll
    for (int off = 8; off; off >>= 1) {
        lsum += __shfl_xor(lsum, off);
        a0 += __shfl_xor(a0, off);
        a1 += __shfl_xor(a1, off);
        a2 += __shfl_xor(a2, off);
    }
    if (l == 0) {
        float inv = 1.f / (lsum + 1e-16f);
        out[(size_t)n * 3 + 0] = a0 * inv + b2[0];
        out[(size_t)n * 3 + 1] = a1 * inv + b2[1];
        out[(size_t)n * 3 + 2] = a2 * inv + b2[2];
    }
}

extern "C" void kernel_launch(void* const* d_in, const int* in_sizes, int n_in,
                              void* d_out, int out_size, void* d_ws, size_t ws_size,
                              hipStream_t stream) {
    const float* x  = (const float*)d_in[0];
    const int*   ei = (const int*)d_in[1];
    const int*   etp = (const int*)d_in[2];
    const float* W1 = (const float*)d_in[3];
    const float* q1 = (const float*)d_in[4];
    const float* k1 = (const float*)d_in[5];
    const float* b1 = (const float*)d_in[6];
    const float* W2 = (const float*)d_in[7];
    const float* q2 = (const float*)d_in[8];
    const float* k2 = (const float*)d_in[9];
    const float* b2 = (const float*)d_in[10];
    float* out = (float*)d_out;

    const int n_nodes = in_sizes[0] / IN_DIM;  // 50000
    const int ecnt    = in_sizes[2];           // 800000
    const int* srcp = ei;
    const int* dstp = ei + ecnt;

    char* wp = (char*)d_ws;
    auto alloc = [&](size_t bytes) -> char* {
        char* p = wp;
        wp += (bytes + 255) & ~(size_t)255;
        return p;
    };
    float* xr2p  = (float*)alloc((size_t)2 * n_nodes * 4 * 4);
    float* sq1   = (float*)alloc((size_t)2 * n_nodes * 4);
    float* sk1   = (float*)alloc((size_t)2 * n_nodes * 4);
    float* sq2   = (float*)alloc((size_t)2 * n_nodes * 4);
    float* wq1   = (float*)alloc(32 * 4);
    float* wk1   = (float*)alloc(32 * 4);
    float* Mbuf  = (float*)alloc(320 * 4);
    float* Cbuf  = (float*)alloc(10 * 4);
    int* counts  = (int*)alloc((size_t)n_nodes * 4);
    int* exoff   = (int*)alloc((size_t)n_nodes * 4);
    int* blockSums = (int*)alloc(512);
    int* blockBase = (int*)alloc(512);
    int* offsets = (int*)alloc((size_t)(n_nodes + 1) * 4);
    int* rank    = (int*)alloc((size_t)ecnt * 4);
    int* sorted  = (int*)alloc((size_t)ecnt * 4);

    int nblk = (n_nodes + 255) / 256;   // 196: covers counts zeroing + precompute waves
    int eblk = (ecnt + 255) / 256;
    int nblk_scan = (n_nodes + 511) / 512;

    k_pre<<<nblk, 256, 0, stream>>>(W1, q1, k1, b1, W2, q2, k2, wq1, wk1, Mbuf, Cbuf,
                                    counts, n_nodes);
    k_prep<<<eblk, 256, 0, stream>>>(x, wq1, wk1, sq1, sk1, dstp, counts, rank, n_nodes, ecnt);
    k_scan1<<<nblk_scan, 512, 0, stream>>>(counts, exoff, blockSums, n_nodes);
    k_scan2<<<1, 128, 0, stream>>>(blockSums, blockBase, nblk_scan);
    k_scan3<<<(n_nodes + 256) / 256, 256, 0, stream>>>(exoff, blockBase, offsets, n_nodes, ecnt);
    k_scatter<<<eblk, 256, 0, stream>>>(srcp, dstp, etp, offsets, rank, sorted, ecnt);

    k_layer1<<<(n_nodes + 3) / 4, 256, 0, stream>>>(offsets, sorted, sq1, sk1, x, Mbuf, Cbuf,
                                                    xr2p, sq2, n_nodes);
    k_node2<<<(n_nodes * 16 + 255) / 256, 256, 0, stream>>>(offsets, sorted, sq2, xr2p, b2,
                                                            out, n_nodes);
}